// Round 23
// baseline (116.650 us; speedup 1.0000x reference)
//
#include <hip/hip_runtime.h>
#include <hip/hip_bf16.h>
#include <cstdint>

// Toy MultiHeadAttention: B=2, L=2048, D=1024, H=16, HD=64, causal, eval (no dropout)
// Pipeline: fp32->bf16 converts; QKV GEMM (bf16 MFMA, T2-swizzled LDS, 64x64 tile);
// causal flash attention (KVBLK=64 LDS-shared K/V, defer-max, zero-shuffle x16 PV,
// PAIRED strip-groups p & 31-p for uniform 33-tile blocks); out GEMM (64x64) + bias.

typedef __attribute__((ext_vector_type(8))) short sh8;    // 8 bf16 (4 VGPRs) for 16x16x32
typedef __attribute__((ext_vector_type(4))) short sh4;    // 4 bf16 (2 VGPRs) for 16x16x16
typedef __attribute__((ext_vector_type(4))) float f32x4;  // MFMA C/D frag

__device__ __forceinline__ unsigned short f2b(float f) {  // fp32 -> bf16 RNE
  unsigned int u = __float_as_uint(f);
  u += 0x7FFFu + ((u >> 16) & 1u);
  return (unsigned short)(u >> 16);
}

__device__ __forceinline__ unsigned int pack2(float lo, float hi) {  // 2xbf16 in u32
  return (unsigned int)f2b(lo) | ((unsigned int)f2b(hi) << 16);
}

__device__ __forceinline__ f32x4 mfma16x16x16(sh4 a, sh4 b, f32x4 c) {
#if __has_builtin(__builtin_amdgcn_mfma_f32_16x16x16bf16_1k)
  return __builtin_amdgcn_mfma_f32_16x16x16bf16_1k(a, b, c, 0, 0, 0);
#else
  asm volatile("v_mfma_f32_16x16x16_bf16 %0, %1, %2, %0" : "+v"(c) : "v"(a), "v"(b));
  return c;
#endif
}

__device__ __forceinline__ void gload_lds16(const void* g, void* l) {
  __builtin_amdgcn_global_load_lds((__attribute__((address_space(1))) void*)g,
                                   (__attribute__((address_space(3))) void*)l,
                                   16, 0, 0);
}

// ---------------- fp32 -> bf16 convert (vectorized) ----------------
__global__ __launch_bounds__(256) void k_cvt(const float* __restrict__ in,
                                             unsigned short* __restrict__ out, int n) {
  int idx = (blockIdx.x * 256 + threadIdx.x) * 4;
  if (idx >= n) return;
  float4 v = *(const float4*)&in[idx];
  union { unsigned short u[4]; uint2 w; } r;
  r.u[0] = f2b(v.x); r.u[1] = f2b(v.y); r.u[2] = f2b(v.z); r.u[3] = f2b(v.w);
  *(uint2*)&out[idx] = r.w;
}

// ---------------- templated GEMM core: C[BM x BN] = A[M,K] * B[N,K]^T ----------------
// BM = MT*32, BN = NT*32; 256 thr = 4 waves in 2x2; wave owns (MT*16)x(NT*16).
// T2 XOR-swizzled LDS (r16/r18/r19/r20-validated), single-buffer staging.
template<int MT, int NT>
__device__ __forceinline__ void gemm_bt_core(
    const unsigned short* __restrict__ A,   // [M][K] bf16 row-major
    const unsigned short* __restrict__ B,   // [N][K] bf16 row-major
    int K, int m0, int n0,
    unsigned short* ldsA, unsigned short* ldsB,
    f32x4 acc[MT][NT]) {
  constexpr int TA = MT;          // A granule-loads per thread (MT*32 rows * 8 / 256)
  constexpr int TB = NT;
  const int tid  = threadIdx.x;
  const int wv   = tid >> 6;
  const int lane = tid & 63;
  const int wm = (wv >> 1) * (MT * 16);
  const int wn = (wv & 1) * (NT * 16);
  const int fr = lane & 15;
  const int g  = lane >> 4;

  for (int k0 = 0; k0 < K; k0 += 64) {
#pragma unroll
    for (int t = 0; t < TA; ++t) {
      int gi = t * 256 + tid;               // granule index (wave-contiguous dest)
      int r = gi >> 3, c = gi & 7;
      gload_lds16(&A[(size_t)(m0 + r) * K + k0 + ((c ^ (r & 7)) << 3)], &ldsA[gi * 8]);
    }
#pragma unroll
    for (int t = 0; t < TB; ++t) {
      int gi = t * 256 + tid;
      int r = gi >> 3, c = gi & 7;
      gload_lds16(&B[(size_t)(n0 + r) * K + k0 + ((c ^ (r & 7)) << 3)], &ldsB[gi * 8]);
    }
    __syncthreads();
#pragma unroll
    for (int ks = 0; ks < 2; ++ks) {
      sh8 af[MT], bf[NT];
#pragma unroll
      for (int mt = 0; mt < MT; ++mt)
        af[mt] = *(const sh8*)&ldsA[(wm + mt * 16 + fr) * 64 +
                                    ((((ks << 2) + g) ^ (fr & 7)) << 3)];
#pragma unroll
      for (int nt = 0; nt < NT; ++nt)
        bf[nt] = *(const sh8*)&ldsB[(wn + nt * 16 + fr) * 64 +
                                    ((((ks << 2) + g) ^ (fr & 7)) << 3)];
#pragma unroll
      for (int mt = 0; mt < MT; ++mt)
#pragma unroll
        for (int nt = 0; nt < NT; ++nt)
          acc[mt][nt] = __builtin_amdgcn_mfma_f32_16x16x32_bf16(af[mt], bf[nt], acc[mt][nt], 0, 0, 0);
    }
    __syncthreads();
  }
}

// ---------------- QKV projection + scatter (BM=64, BN=64 -> 3072 blocks) ----------
__global__ __launch_bounds__(256, 8) void k_qkv_gemm(
    const unsigned short* __restrict__ xb, const unsigned short* __restrict__ wq,
    unsigned short* __restrict__ Q, unsigned short* __restrict__ Kc,
    unsigned short* __restrict__ Vt) {
  __shared__ __align__(16) unsigned short ldsA[64 * 64];    // 8KB
  __shared__ __align__(16) unsigned short ldsB[64 * 64];    // 8KB
  f32x4 acc[2][2];
  const f32x4 fz = {0.f, 0.f, 0.f, 0.f};
#pragma unroll
  for (int i = 0; i < 2; ++i)
#pragma unroll
    for (int j = 0; j < 2; ++j) acc[i][j] = fz;

  const int m0 = blockIdx.x * 64, n0 = blockIdx.y * 64;
  gemm_bt_core<2, 2>(xb, wq, 1024, m0, n0, ldsA, ldsB, acc);

  const int tid = threadIdx.x, wv = tid >> 6, lane = tid & 63;
  const int wm = (wv >> 1) << 5, wn = (wv & 1) << 5;
  const int r4 = (lane >> 4) << 2, fr = lane & 15;
#pragma unroll
  for (int mt = 0; mt < 2; ++mt)
#pragma unroll
    for (int nt = 0; nt < 2; ++nt) {
      const int row0 = m0 + wm + mt * 16 + r4;   // 4-row group, never straddles b
      const int col  = n0 + wn + nt * 16 + fr;   // n in [0,3072)
      const int b = row0 >> 11;
      const int which = col >> 10, rem = col & 1023;
      const int h = rem >> 6, hd = rem & 63;
      const size_t bh = (size_t)(b * 16 + h);
      if (which == 2) {
        const size_t vb = (bh * 64 + hd) * 2048 + (row0 & 2047);
        *(unsigned int*)&Vt[vb]     = pack2(acc[mt][nt][0], acc[mt][nt][1]);
        *(unsigned int*)&Vt[vb + 2] = pack2(acc[mt][nt][2], acc[mt][nt][3]);
      } else {
#pragma unroll
        for (int i = 0; i < 4; ++i) {
          const int lq = (row0 + i) & 2047;
          float v = acc[mt][nt][i];
          if (which == 0) Q [(bh * 2048 + lq) * 64 + hd] = f2b(v * 0.125f);
          else            Kc[(bh * 2048 + lq) * 64 + hd] = f2b(v);
        }
      }
    }
}

// ---------------- causal flash attention (KVBLK=64, paired strip-groups) ----------
// grid: 512 blocks x 256 thr; blockIdx = pr*32 + bh (pr = 0..15, bh fastest).
// Block processes strip-group pr (pr+1 tiles) THEN group 31-pr (32-pr tiles):
// uniform 33 tiles/block -> no inter-CU imbalance. Per-half body == r20-PASSING
// kernel (LDS-shared K/V dbuf staging, 4 QK sub-tiles, defer-max T13, zero-shuffle
// x16 PV, per-lane lp). Barrier between halves protects LDS reuse.
__global__ __launch_bounds__(256, 4) void k_attn(
    const unsigned short* __restrict__ Q, const unsigned short* __restrict__ Kc,
    const unsigned short* __restrict__ Vt, unsigned short* __restrict__ attn) {
  __shared__ __align__(16) unsigned short kbuf[2][64 * 64];   // 8KB per buf
  __shared__ __align__(16) unsigned short vbuf[2][64 * 64];   // 8KB per buf

  const int bh = blockIdx.x & 31;
  const int pr = blockIdx.x >> 5;              // 0..15
  const int wv = threadIdx.x >> 6, lane = threadIdx.x & 63;
  const int tid = threadIdx.x;
  const int b = bh >> 4, h = bh & 15;
  const unsigned short* Qb = Q  + (size_t)bh * 2048 * 64;
  const unsigned short* Kb = Kc + (size_t)bh * 2048 * 64;
  const unsigned short* Vb = Vt + (size_t)bh * 64 * 2048;
  const int fr = lane & 15, g = lane >> 4;
  const int fk = g << 3, r4 = g << 2;
  const f32x4 fz = {0.f, 0.f, 0.f, 0.f};

  // staging map: 512 granules per buffer, 2 per thread
  const int sgr0 = tid >> 3,         sgc0 = tid & 7;         // granule (row, col)
  const int sgr1 = (tid + 256) >> 3, sgc1 = tid & 7;         // second granule

#pragma unroll 1
  for (int half = 0; half < 2; ++half) {
    const int grp = half ? (31 - pr) : pr;     // pair: pr+1 and 32-pr tiles = 33
    const int strip = (grp << 2) + wv;         // 0..127
    const int qw = strip << 4;
    const int njm = grp + 1;                   // uniform tile count (incl. diagonal)

    sh8 qf[2];
#pragma unroll
    for (int ks = 0; ks < 2; ++ks)
      qf[ks] = *(const sh8*)&Qb[(size_t)(qw + fr) * 64 + ks * 32 + fk];

    f32x4 o[4];
#pragma unroll
    for (int i = 0; i < 4; ++i) o[i] = fz;
    float m_i = -1e30f, lp = 0.f;

    if (half) __syncthreads();   // all half-0 LDS reads done before restaging

    // stage tile 0 into buf 0
    gload_lds16(&Kb[(size_t)sgr0 * 64 + ((sgc0 ^ (sgr0 & 7)) << 3)], &kbuf[0][tid * 8]);
    gload_lds16(&Kb[(size_t)sgr1 * 64 + ((sgc1 ^ (sgr1 & 7)) << 3)], &kbuf[0][(tid + 256) * 8]);
    gload_lds16(&Vb[(size_t)sgr0 * 2048 + ((sgc0 ^ (sgr0 & 7)) << 3)], &vbuf[0][tid * 8]);
    gload_lds16(&Vb[(size_t)sgr1 * 2048 + ((sgc1 ^ (sgr1 & 7)) << 3)], &vbuf[0][(tid + 256) * 8]);

    for (int j = 0; j < njm; ++j) {
      __syncthreads();   // stage(j) complete (vmcnt drain); compute(j-1) done
      if (j + 1 < njm) {
        const int kvn = (j + 1) << 6;
        const int nb = (j + 1) & 1;
        gload_lds16(&Kb[(size_t)(kvn + sgr0) * 64 + ((sgc0 ^ (sgr0 & 7)) << 3)], &kbuf[nb][tid * 8]);
        gload_lds16(&Kb[(size_t)(kvn + sgr1) * 64 + ((sgc1 ^ (sgr1 & 7)) << 3)], &kbuf[nb][(tid + 256) * 8]);
        gload_lds16(&Vb[(size_t)sgr0 * 2048 + kvn + ((sgc0 ^ (sgr0 & 7)) << 3)], &vbuf[nb][tid * 8]);
        gload_lds16(&Vb[(size_t)sgr1 * 2048 + kvn + ((sgc1 ^ (sgr1 & 7)) << 3)], &vbuf[nb][(tid + 256) * 8]);
      }
      const int kvb = j << 6;
      const unsigned short* kb = kbuf[j & 1];
      const unsigned short* vb = vbuf[j & 1];
      // QK^T swapped, 4 independent sub-tiles: s[t] rows kv = kvb+16t+4g+i, col q = fr
      f32x4 s[4];
#pragma unroll
      for (int t = 0; t < 4; ++t) s[t] = fz;
#pragma unroll
      for (int ks = 0; ks < 2; ++ks)
#pragma unroll
        for (int t = 0; t < 4; ++t) {
          sh8 kf = *(const sh8*)&kb[(t * 16 + fr) * 64 + ((((ks << 2) + g) ^ (fr & 7)) << 3)];
          s[t] = __builtin_amdgcn_mfma_f32_16x16x32_bf16(kf, qf[ks], s[t], 0, 0, 0);
        }

      if (j == njm - 1) {  // diagonal tile: causal mask (kv > q)
#pragma unroll
        for (int t = 0; t < 4; ++t)
#pragma unroll
          for (int i = 0; i < 4; ++i)
            if (kvb + t * 16 + r4 + i > qw + fr) s[t][i] = -1e30f;
      }
      // defer-max (T13): common path has NO cross-lane ops
      float pm = s[0][0];
#pragma unroll
      for (int t = 0; t < 4; ++t)
#pragma unroll
        for (int i = 0; i < 4; ++i) pm = fmaxf(pm, s[t][i]);
      if (!__all(pm - m_i <= 8.0f)) {   // rare: full row-max reduce + rescale
        float rm = fmaxf(pm, __shfl_xor(pm, 16, 64));
        rm = fmaxf(rm, __shfl_xor(rm, 32, 64));
        const float mn = fmaxf(m_i, rm);
        const float sc = __expf(m_i - mn);
        m_i = mn;
        lp *= sc;
#pragma unroll
        for (int hb = 0; hb < 4; ++hb)
#pragma unroll
          for (int i = 0; i < 4; ++i) o[hb][i] *= sc;
      }
      // exp in place; lp per-lane partial
#pragma unroll
      for (int t = 0; t < 4; ++t) {
#pragma unroll
        for (int i = 0; i < 4; ++i) s[t][i] = __expf(s[t][i] - m_i);
        lp += (s[t][0] + s[t][1]) + (s[t][2] + s[t][3]);
      }
      // PV per sub-tile: P already in x16 B-frag layout (col q=fr, k=4g+j)
#pragma unroll
      for (int t = 0; t < 4; ++t) {
        union { unsigned int w[2]; sh4 v; } pb;
        pb.w[0] = pack2(s[t][0], s[t][1]);
        pb.w[1] = pack2(s[t][2], s[t][3]);
#pragma unroll
        for (int hb = 0; hb < 4; ++hb) {
          sh4 vf = *(const sh4*)&vb[(hb * 16 + fr) * 64 +
                                    ((((t << 1) + (g >> 1)) ^ (fr & 7)) << 3) + ((g & 1) << 2)];
          o[hb] = mfma16x16x16(vf, pb.v, o[hb]);
        }
      }
    }

    // epilogue: reduce per-lane lp across the 4 g-groups once
    float l = lp;
    l += __shfl_xor(l, 16, 64);
    l += __shfl_xor(l, 32, 64);
    const float inv = 1.0f / l;
    const size_t base = ((size_t)(b * 2048 + qw + fr)) * 1024 + h * 64;
#pragma unroll
    for (int hb = 0; hb < 4; ++hb)
#pragma unroll
      for (int i2 = 0; i2 < 2; ++i2) {
        unsigned int pw = pack2(o[hb][2 * i2] * inv, o[hb][2 * i2 + 1] * inv);
        *(unsigned int*)&attn[base + hb * 16 + r4 + 2 * i2] = pw;
      }
  }
}

// ---------------- output projection + bias (BM=64, BN=64 -> 1024 blocks) ----------
__global__ __launch_bounds__(256, 5) void k_out_gemm(
    const unsigned short* __restrict__ attn, const unsigned short* __restrict__ wo,
    const float* __restrict__ bias, float* __restrict__ out) {
  __shared__ __align__(16) unsigned short ldsA[64 * 64];    // 8KB
  __shared__ __align__(16) unsigned short ldsB[64 * 64];    // 8KB
  f32x4 acc[2][2];
  const f32x4 fz = {0.f, 0.f, 0.f, 0.f};
#pragma unroll
  for (int i = 0; i < 2; ++i)
#pragma unroll
    for (int j = 0; j < 2; ++j) acc[i][j] = fz;

  const int m0 = blockIdx.x * 64, n0 = blockIdx.y * 64;
  gemm_bt_core<2, 2>(attn, wo, 1024, m0, n0, ldsA, ldsB, acc);

  const int tid = threadIdx.x, wv = tid >> 6, lane = tid & 63;
  const int wm = (wv >> 1) << 5, wn = (wv & 1) << 5;
  const int r4 = (lane >> 4) << 2, fr = lane & 15;
#pragma unroll
  for (int mt = 0; mt < 2; ++mt)
#pragma unroll
    for (int nt = 0; nt < 2; ++nt)
#pragma unroll
      for (int i = 0; i < 4; ++i) {
        int row = m0 + wm + mt * 16 + r4 + i;
        int col = n0 + wn + nt * 16 + fr;
        out[(size_t)row * 1024 + col] = acc[mt][nt][i] + bias[col];
      }
}

// ---------------- launch ----------------
extern "C" void kernel_launch(void* const* d_in, const int* in_sizes, int n_in,
                              void* d_out, int out_size, void* d_ws, size_t ws_size,
                              hipStream_t stream) {
  const float* x     = (const float*)d_in[0];
  const float* qkv_w = (const float*)d_in[1];
  const float* out_w = (const float*)d_in[2];
  const float* out_b = (const float*)d_in[3];
  float* out = (float*)d_out;

  unsigned short* ws   = (unsigned short*)d_ws;
  unsigned short* xb   = ws;                        // 4096*1024
  unsigned short* wq   = xb  + 4096 * 1024;         // 3072*1024
  unsigned short* wo   = wq  + 3072 * 1024;         // 1024*1024
  unsigned short* Qs   = wo  + 1024 * 1024;         // 32*2048*64
  unsigned short* Ks   = Qs  + 32 * 2048 * 64;      // 32*2048*64
  unsigned short* Vts  = Ks  + 32 * 2048 * 64;      // 32*64*2048
  unsigned short* attn = Vts + 32 * 64 * 2048;      // 4096*1024

  k_cvt<<<4096, 256, 0, stream>>>(x,     xb, 4096 * 1024);
  k_cvt<<<3072, 256, 0, stream>>>(qkv_w, wq, 3072 * 1024);
  k_cvt<<<1024, 256, 0, stream>>>(out_w, wo, 1024 * 1024);
  k_qkv_gemm<<<dim3(64, 48), 256, 0, stream>>>(xb, wq, Qs, Ks, Vts);
  k_attn<<<512, 256, 0, stream>>>(Qs, Ks, Vts, attn);
  k_out_gemm<<<dim3(64, 16), 256, 0, stream>>>(attn, wo, out_b, out);
}

// Round 24
// 111.042 us; speedup vs baseline: 1.0505x; 1.0505x over previous
//
#include <hip/hip_runtime.h>
#include <hip/hip_bf16.h>
#include <cstdint>

// Toy MultiHeadAttention: B=2, L=2048, D=1024, H=16, HD=64, causal, eval (no dropout)
// Pipeline: fp32->bf16 converts; QKV GEMM (bf16 MFMA, T2-swizzled LDS, 64x64 tile;
// Q pre-scaled by 0.125*log2e for log2-domain softmax); causal flash attention
// (KVBLK=64 LDS-shared K/V, FIXED-MAX log2-domain softmax, zero-shuffle x16 PV);
// out GEMM (64x64) + bias (fp32 out).

typedef __attribute__((ext_vector_type(8))) short sh8;    // 8 bf16 (4 VGPRs) for 16x16x32
typedef __attribute__((ext_vector_type(4))) short sh4;    // 4 bf16 (2 VGPRs) for 16x16x16
typedef __attribute__((ext_vector_type(4))) float f32x4;  // MFMA C/D frag

__device__ __forceinline__ unsigned short f2b(float f) {  // fp32 -> bf16 RNE
  unsigned int u = __float_as_uint(f);
  u += 0x7FFFu + ((u >> 16) & 1u);
  return (unsigned short)(u >> 16);
}

__device__ __forceinline__ unsigned int pack2(float lo, float hi) {  // 2xbf16 in u32
  return (unsigned int)f2b(lo) | ((unsigned int)f2b(hi) << 16);
}

__device__ __forceinline__ f32x4 mfma16x16x16(sh4 a, sh4 b, f32x4 c) {
#if __has_builtin(__builtin_amdgcn_mfma_f32_16x16x16bf16_1k)
  return __builtin_amdgcn_mfma_f32_16x16x16bf16_1k(a, b, c, 0, 0, 0);
#else
  asm volatile("v_mfma_f32_16x16x16_bf16 %0, %1, %2, %0" : "+v"(c) : "v"(a), "v"(b));
  return c;
#endif
}

__device__ __forceinline__ void gload_lds16(const void* g, void* l) {
  __builtin_amdgcn_global_load_lds((__attribute__((address_space(1))) void*)g,
                                   (__attribute__((address_space(3))) void*)l,
                                   16, 0, 0);
}

// ---------------- fp32 -> bf16 convert (vectorized) ----------------
__global__ __launch_bounds__(256) void k_cvt(const float* __restrict__ in,
                                             unsigned short* __restrict__ out, int n) {
  int idx = (blockIdx.x * 256 + threadIdx.x) * 4;
  if (idx >= n) return;
  float4 v = *(const float4*)&in[idx];
  union { unsigned short u[4]; uint2 w; } r;
  r.u[0] = f2b(v.x); r.u[1] = f2b(v.y); r.u[2] = f2b(v.z); r.u[3] = f2b(v.w);
  *(uint2*)&out[idx] = r.w;
}

// ---------------- templated GEMM core: C[BM x BN] = A[M,K] * B[N,K]^T ----------------
// BM = MT*32, BN = NT*32; 256 thr = 4 waves in 2x2; wave owns (MT*16)x(NT*16).
// T2 XOR-swizzled LDS (r16/r18/r19/r20-validated), single-buffer staging.
template<int MT, int NT>
__device__ __forceinline__ void gemm_bt_core(
    const unsigned short* __restrict__ A,   // [M][K] bf16 row-major
    const unsigned short* __restrict__ B,   // [N][K] bf16 row-major
    int K, int m0, int n0,
    unsigned short* ldsA, unsigned short* ldsB,
    f32x4 acc[MT][NT]) {
  constexpr int TA = MT;          // A granule-loads per thread (MT*32 rows * 8 / 256)
  constexpr int TB = NT;
  const int tid  = threadIdx.x;
  const int wv   = tid >> 6;
  const int lane = tid & 63;
  const int wm = (wv >> 1) * (MT * 16);
  const int wn = (wv & 1) * (NT * 16);
  const int fr = lane & 15;
  const int g  = lane >> 4;

  for (int k0 = 0; k0 < K; k0 += 64) {
#pragma unroll
    for (int t = 0; t < TA; ++t) {
      int gi = t * 256 + tid;               // granule index (wave-contiguous dest)
      int r = gi >> 3, c = gi & 7;
      gload_lds16(&A[(size_t)(m0 + r) * K + k0 + ((c ^ (r & 7)) << 3)], &ldsA[gi * 8]);
    }
#pragma unroll
    for (int t = 0; t < TB; ++t) {
      int gi = t * 256 + tid;
      int r = gi >> 3, c = gi & 7;
      gload_lds16(&B[(size_t)(n0 + r) * K + k0 + ((c ^ (r & 7)) << 3)], &ldsB[gi * 8]);
    }
    __syncthreads();
#pragma unroll
    for (int ks = 0; ks < 2; ++ks) {
      sh8 af[MT], bf[NT];
#pragma unroll
      for (int mt = 0; mt < MT; ++mt)
        af[mt] = *(const sh8*)&ldsA[(wm + mt * 16 + fr) * 64 +
                                    ((((ks << 2) + g) ^ (fr & 7)) << 3)];
#pragma unroll
      for (int nt = 0; nt < NT; ++nt)
        bf[nt] = *(const sh8*)&ldsB[(wn + nt * 16 + fr) * 64 +
                                    ((((ks << 2) + g) ^ (fr & 7)) << 3)];
#pragma unroll
      for (int mt = 0; mt < MT; ++mt)
#pragma unroll
        for (int nt = 0; nt < NT; ++nt)
          acc[mt][nt] = __builtin_amdgcn_mfma_f32_16x16x32_bf16(af[mt], bf[nt], acc[mt][nt], 0, 0, 0);
    }
    __syncthreads();
  }
}

// ---------------- QKV projection + scatter (BM=64, BN=64 -> 3072 blocks) ----------
// Q pre-scaled by 0.125 * log2(e) so attention scores land in the log2 domain.
__global__ __launch_bounds__(256, 8) void k_qkv_gemm(
    const unsigned short* __restrict__ xb, const unsigned short* __restrict__ wq,
    unsigned short* __restrict__ Q, unsigned short* __restrict__ Kc,
    unsigned short* __restrict__ Vt) {
  __shared__ __align__(16) unsigned short ldsA[64 * 64];    // 8KB
  __shared__ __align__(16) unsigned short ldsB[64 * 64];    // 8KB
  f32x4 acc[2][2];
  const f32x4 fz = {0.f, 0.f, 0.f, 0.f};
#pragma unroll
  for (int i = 0; i < 2; ++i)
#pragma unroll
    for (int j = 0; j < 2; ++j) acc[i][j] = fz;

  const int m0 = blockIdx.x * 64, n0 = blockIdx.y * 64;
  gemm_bt_core<2, 2>(xb, wq, 1024, m0, n0, ldsA, ldsB, acc);

  const int tid = threadIdx.x, wv = tid >> 6, lane = tid & 63;
  const int wm = (wv >> 1) << 5, wn = (wv & 1) << 5;
  const int r4 = (lane >> 4) << 2, fr = lane & 15;
#pragma unroll
  for (int mt = 0; mt < 2; ++mt)
#pragma unroll
    for (int nt = 0; nt < 2; ++nt) {
      const int row0 = m0 + wm + mt * 16 + r4;   // 4-row group, never straddles b
      const int col  = n0 + wn + nt * 16 + fr;   // n in [0,3072)
      const int b = row0 >> 11;
      const int which = col >> 10, rem = col & 1023;
      const int h = rem >> 6, hd = rem & 63;
      const size_t bh = (size_t)(b * 16 + h);
      if (which == 2) {
        const size_t vb = (bh * 64 + hd) * 2048 + (row0 & 2047);
        *(unsigned int*)&Vt[vb]     = pack2(acc[mt][nt][0], acc[mt][nt][1]);
        *(unsigned int*)&Vt[vb + 2] = pack2(acc[mt][nt][2], acc[mt][nt][3]);
      } else {
#pragma unroll
        for (int i = 0; i < 4; ++i) {
          const int lq = (row0 + i) & 2047;
          float v = acc[mt][nt][i];
          if (which == 0) Q [(bh * 2048 + lq) * 64 + hd] = f2b(v * 0.18033688f);  // 0.125*log2e
          else            Kc[(bh * 2048 + lq) * 64 + hd] = f2b(v);
        }
      }
    }
}

// ---------------- causal flash attention (KVBLK=64, fixed-max log2 softmax) --------
// grid: 1024 blocks x 256 thr; blockIdx = gIdx*32 + bh; grp = 31 - gIdx (longest
// first, bh fastest). Wave wv owns strip = grp*4 + wv; njm = grp+1 tiles (uniform).
// Per 64-kv tile: K/V staged into dbuf LDS; 4 QK sub-tiles; FIXED-MAX softmax:
// p = exp2(s2 - 32) with s2 in log2 domain (Q pre-scaled by log2e) -- softmax ratio
// mathematically identical to reference (constant shift), no max tracking, no
// rescale, no cross-lane ops until the final lp reduce. Zero-shuffle x16 PV.
__global__ __launch_bounds__(256, 4) void k_attn(
    const unsigned short* __restrict__ Q, const unsigned short* __restrict__ Kc,
    const unsigned short* __restrict__ Vt, unsigned short* __restrict__ attn) {
  __shared__ __align__(16) unsigned short kbuf[2][64 * 64];   // 8KB per buf
  __shared__ __align__(16) unsigned short vbuf[2][64 * 64];   // 8KB per buf

  const int bh  = blockIdx.x & 31;
  const int grp = 31 - (blockIdx.x >> 5);      // 0..31, longest first
  const int wv = threadIdx.x >> 6, lane = threadIdx.x & 63;
  const int tid = threadIdx.x;
  const int strip = (grp << 2) + wv;           // 0..127
  const int qw = strip << 4;
  const int b = bh >> 4, h = bh & 15;
  const unsigned short* Qb = Q  + (size_t)bh * 2048 * 64;
  const unsigned short* Kb = Kc + (size_t)bh * 2048 * 64;
  const unsigned short* Vb = Vt + (size_t)bh * 64 * 2048;
  const int fr = lane & 15, g = lane >> 4;
  const int fk = g << 3, r4 = g << 2;
  const f32x4 fz = {0.f, 0.f, 0.f, 0.f};
  const float M2 = 32.0f;                      // fixed max, log2 domain (natural ~22.2)

  // staging map: 512 granules per buffer, 2 per thread
  const int sgr0 = tid >> 3,         sgc0 = tid & 7;         // granule (row, col)
  const int sgr1 = (tid + 256) >> 3, sgc1 = tid & 7;         // second granule

  sh8 qf[2];
#pragma unroll
  for (int ks = 0; ks < 2; ++ks)
    qf[ks] = *(const sh8*)&Qb[(size_t)(qw + fr) * 64 + ks * 32 + fk];

  f32x4 o[4];
#pragma unroll
  for (int i = 0; i < 4; ++i) o[i] = fz;
  float lp = 0.f;

  const int njm = grp + 1;                     // uniform tile count (incl. diagonal)

  // stage tile 0 into buf 0
  gload_lds16(&Kb[(size_t)sgr0 * 64 + ((sgc0 ^ (sgr0 & 7)) << 3)], &kbuf[0][tid * 8]);
  gload_lds16(&Kb[(size_t)sgr1 * 64 + ((sgc1 ^ (sgr1 & 7)) << 3)], &kbuf[0][(tid + 256) * 8]);
  gload_lds16(&Vb[(size_t)sgr0 * 2048 + ((sgc0 ^ (sgr0 & 7)) << 3)], &vbuf[0][tid * 8]);
  gload_lds16(&Vb[(size_t)sgr1 * 2048 + ((sgc1 ^ (sgr1 & 7)) << 3)], &vbuf[0][(tid + 256) * 8]);

  for (int j = 0; j < njm; ++j) {
    __syncthreads();   // stage(j) complete (vmcnt drain); compute(j-1) done
    if (j + 1 < njm) {
      const int kvn = (j + 1) << 6;
      const int nb = (j + 1) & 1;
      gload_lds16(&Kb[(size_t)(kvn + sgr0) * 64 + ((sgc0 ^ (sgr0 & 7)) << 3)], &kbuf[nb][tid * 8]);
      gload_lds16(&Kb[(size_t)(kvn + sgr1) * 64 + ((sgc1 ^ (sgr1 & 7)) << 3)], &kbuf[nb][(tid + 256) * 8]);
      gload_lds16(&Vb[(size_t)sgr0 * 2048 + kvn + ((sgc0 ^ (sgr0 & 7)) << 3)], &vbuf[nb][tid * 8]);
      gload_lds16(&Vb[(size_t)sgr1 * 2048 + kvn + ((sgc1 ^ (sgr1 & 7)) << 3)], &vbuf[nb][(tid + 256) * 8]);
    }
    const int kvb = j << 6;
    const unsigned short* kb = kbuf[j & 1];
    const unsigned short* vb = vbuf[j & 1];
    // QK^T swapped, 4 independent sub-tiles: s[t] rows kv = kvb+16t+4g+i, col q = fr
    f32x4 s[4];
#pragma unroll
    for (int t = 0; t < 4; ++t) s[t] = fz;
#pragma unroll
    for (int ks = 0; ks < 2; ++ks)
#pragma unroll
      for (int t = 0; t < 4; ++t) {
        sh8 kf = *(const sh8*)&kb[(t * 16 + fr) * 64 + ((((ks << 2) + g) ^ (fr & 7)) << 3)];
        s[t] = __builtin_amdgcn_mfma_f32_16x16x32_bf16(kf, qf[ks], s[t], 0, 0, 0);
      }

    if (j == njm - 1) {  // diagonal tile: causal mask (kv > q)
#pragma unroll
      for (int t = 0; t < 4; ++t)
#pragma unroll
        for (int i = 0; i < 4; ++i)
          if (kvb + t * 16 + r4 + i > qw + fr) s[t][i] = -1e30f;
    }
    // fixed-max softmax: p = exp2(s2 - M2); no max tracking, no branches
#pragma unroll
    for (int t = 0; t < 4; ++t) {
#pragma unroll
      for (int i = 0; i < 4; ++i) s[t][i] = exp2f(s[t][i] - M2);
      lp += (s[t][0] + s[t][1]) + (s[t][2] + s[t][3]);
    }
    // PV per sub-tile: P already in x16 B-frag layout (col q=fr, k=4g+j)
#pragma unroll
    for (int t = 0; t < 4; ++t) {
      union { unsigned int w[2]; sh4 v; } pb;
      pb.w[0] = pack2(s[t][0], s[t][1]);
      pb.w[1] = pack2(s[t][2], s[t][3]);
#pragma unroll
      for (int hb = 0; hb < 4; ++hb) {
        sh4 vf = *(const sh4*)&vb[(hb * 16 + fr) * 64 +
                                  ((((t << 1) + (g >> 1)) ^ (fr & 7)) << 3) + ((g & 1) << 2)];
        o[hb] = mfma16x16x16(vf, pb.v, o[hb]);
      }
    }
  }

  // epilogue: reduce per-lane lp across the 4 g-groups once
  float l = lp;
  l += __shfl_xor(l, 16, 64);
  l += __shfl_xor(l, 32, 64);
  const float inv = 1.0f / l;
  const size_t base = ((size_t)(b * 2048 + qw + fr)) * 1024 + h * 64;
#pragma unroll
  for (int hb = 0; hb < 4; ++hb)
#pragma unroll
    for (int i2 = 0; i2 < 2; ++i2) {
      unsigned int pw = pack2(o[hb][2 * i2] * inv, o[hb][2 * i2 + 1] * inv);
      *(unsigned int*)&attn[base + hb * 16 + r4 + 2 * i2] = pw;
    }
}

// ---------------- output projection + bias (BM=64, BN=64 -> 1024 blocks) ----------
__global__ __launch_bounds__(256, 5) void k_out_gemm(
    const unsigned short* __restrict__ attn, const unsigned short* __restrict__ wo,
    const float* __restrict__ bias, float* __restrict__ out) {
  __shared__ __align__(16) unsigned short ldsA[64 * 64];    // 8KB
  __shared__ __align__(16) unsigned short ldsB[64 * 64];    // 8KB
  f32x4 acc[2][2];
  const f32x4 fz = {0.f, 0.f, 0.f, 0.f};
#pragma unroll
  for (int i = 0; i < 2; ++i)
#pragma unroll
    for (int j = 0; j < 2; ++j) acc[i][j] = fz;

  const int m0 = blockIdx.x * 64, n0 = blockIdx.y * 64;
  gemm_bt_core<2, 2>(attn, wo, 1024, m0, n0, ldsA, ldsB, acc);

  const int tid = threadIdx.x, wv = tid >> 6, lane = tid & 63;
  const int wm = (wv >> 1) << 5, wn = (wv & 1) << 5;
  const int r4 = (lane >> 4) << 2, fr = lane & 15;
#pragma unroll
  for (int mt = 0; mt < 2; ++mt)
#pragma unroll
    for (int nt = 0; nt < 2; ++nt)
#pragma unroll
      for (int i = 0; i < 4; ++i) {
        int row = m0 + wm + mt * 16 + r4 + i;
        int col = n0 + wn + nt * 16 + fr;
        out[(size_t)row * 1024 + col] = acc[mt][nt][i] + bias[col];
      }
}

// ---------------- launch ----------------
extern "C" void kernel_launch(void* const* d_in, const int* in_sizes, int n_in,
                              void* d_out, int out_size, void* d_ws, size_t ws_size,
                              hipStream_t stream) {
  const float* x     = (const float*)d_in[0];
  const float* qkv_w = (const float*)d_in[1];
  const float* out_w = (const float*)d_in[2];
  const float* out_b = (const float*)d_in[3];
  float* out = (float*)d_out;

  unsigned short* ws   = (unsigned short*)d_ws;
  unsigned short* xb   = ws;                        // 4096*1024
  unsigned short* wq   = xb  + 4096 * 1024;         // 3072*1024
  unsigned short* wo   = wq  + 3072 * 1024;         // 1024*1024
  unsigned short* Qs   = wo  + 1024 * 1024;         // 32*2048*64
  unsigned short* Ks   = Qs  + 32 * 2048 * 64;      // 32*2048*64
  unsigned short* Vts  = Ks  + 32 * 2048 * 64;      // 32*64*2048
  unsigned short* attn = Vts + 32 * 64 * 2048;      // 4096*1024

  k_cvt<<<4096, 256, 0, stream>>>(x,     xb, 4096 * 1024);
  k_cvt<<<3072, 256, 0, stream>>>(qkv_w, wq, 3072 * 1024);
  k_cvt<<<1024, 256, 0, stream>>>(out_w, wo, 1024 * 1024);
  k_qkv_gemm<<<dim3(64, 48), 256, 0, stream>>>(xb, wq, Qs, Ks, Vts);
  k_attn<<<1024, 256, 0, stream>>>(Qs, Ks, Vts, attn);
  k_out_gemm<<<dim3(64, 16), 256, 0, stream>>>(attn, wo, out_b, out);
}

// Round 25
// 107.355 us; speedup vs baseline: 1.0866x; 1.0343x over previous
//
#include <hip/hip_runtime.h>
#include <hip/hip_bf16.h>
#include <cstdint>

// Toy MultiHeadAttention: B=2, L=2048, D=1024, H=16, HD=64, causal, eval (no dropout)
// Pipeline: fp32->bf16 converts; QKV GEMM (bf16 MFMA, T2-swizzled LDS, 64x64 tile,
// 3072 blocks for occupancy) with Q/K/Vt scatter epilogue; causal flash attention
// (KVBLK=64 LDS-shared K/V, defer-max, zero-shuffle x16 PV); out GEMM (64x64) + bias.
// == round-22 BEST-MEASURED configuration (106.5 us), restored verbatim ==

typedef __attribute__((ext_vector_type(8))) short sh8;    // 8 bf16 (4 VGPRs) for 16x16x32
typedef __attribute__((ext_vector_type(4))) short sh4;    // 4 bf16 (2 VGPRs) for 16x16x16
typedef __attribute__((ext_vector_type(4))) float f32x4;  // MFMA C/D frag

__device__ __forceinline__ unsigned short f2b(float f) {  // fp32 -> bf16 RNE
  unsigned int u = __float_as_uint(f);
  u += 0x7FFFu + ((u >> 16) & 1u);
  return (unsigned short)(u >> 16);
}

__device__ __forceinline__ unsigned int pack2(float lo, float hi) {  // 2xbf16 in u32
  return (unsigned int)f2b(lo) | ((unsigned int)f2b(hi) << 16);
}

__device__ __forceinline__ f32x4 mfma16x16x16(sh4 a, sh4 b, f32x4 c) {
#if __has_builtin(__builtin_amdgcn_mfma_f32_16x16x16bf16_1k)
  return __builtin_amdgcn_mfma_f32_16x16x16bf16_1k(a, b, c, 0, 0, 0);
#else
  asm volatile("v_mfma_f32_16x16x16_bf16 %0, %1, %2, %0" : "+v"(c) : "v"(a), "v"(b));
  return c;
#endif
}

__device__ __forceinline__ void gload_lds16(const void* g, void* l) {
  __builtin_amdgcn_global_load_lds((__attribute__((address_space(1))) void*)g,
                                   (__attribute__((address_space(3))) void*)l,
                                   16, 0, 0);
}

// ---------------- fp32 -> bf16 convert (vectorized) ----------------
__global__ __launch_bounds__(256) void k_cvt(const float* __restrict__ in,
                                             unsigned short* __restrict__ out, int n) {
  int idx = (blockIdx.x * 256 + threadIdx.x) * 4;
  if (idx >= n) return;
  float4 v = *(const float4*)&in[idx];
  union { unsigned short u[4]; uint2 w; } r;
  r.u[0] = f2b(v.x); r.u[1] = f2b(v.y); r.u[2] = f2b(v.z); r.u[3] = f2b(v.w);
  *(uint2*)&out[idx] = r.w;
}

// ---------------- templated GEMM core: C[BM x BN] = A[M,K] * B[N,K]^T ----------------
// BM = MT*32, BN = NT*32; 256 thr = 4 waves in 2x2; wave owns (MT*16)x(NT*16).
// T2 XOR-swizzled LDS (r16/r18/r19/r20-validated), single-buffer staging.
template<int MT, int NT>
__device__ __forceinline__ void gemm_bt_core(
    const unsigned short* __restrict__ A,   // [M][K] bf16 row-major
    const unsigned short* __restrict__ B,   // [N][K] bf16 row-major
    int K, int m0, int n0,
    unsigned short* ldsA, unsigned short* ldsB,
    f32x4 acc[MT][NT]) {
  constexpr int TA = MT;          // A granule-loads per thread (MT*32 rows * 8 / 256)
  constexpr int TB = NT;
  const int tid  = threadIdx.x;
  const int wv   = tid >> 6;
  const int lane = tid & 63;
  const int wm = (wv >> 1) * (MT * 16);
  const int wn = (wv & 1) * (NT * 16);
  const int fr = lane & 15;
  const int g  = lane >> 4;

  for (int k0 = 0; k0 < K; k0 += 64) {
#pragma unroll
    for (int t = 0; t < TA; ++t) {
      int gi = t * 256 + tid;               // granule index (wave-contiguous dest)
      int r = gi >> 3, c = gi & 7;
      gload_lds16(&A[(size_t)(m0 + r) * K + k0 + ((c ^ (r & 7)) << 3)], &ldsA[gi * 8]);
    }
#pragma unroll
    for (int t = 0; t < TB; ++t) {
      int gi = t * 256 + tid;
      int r = gi >> 3, c = gi & 7;
      gload_lds16(&B[(size_t)(n0 + r) * K + k0 + ((c ^ (r & 7)) << 3)], &ldsB[gi * 8]);
    }
    __syncthreads();
#pragma unroll
    for (int ks = 0; ks < 2; ++ks) {
      sh8 af[MT], bf[NT];
#pragma unroll
      for (int mt = 0; mt < MT; ++mt)
        af[mt] = *(const sh8*)&ldsA[(wm + mt * 16 + fr) * 64 +
                                    ((((ks << 2) + g) ^ (fr & 7)) << 3)];
#pragma unroll
      for (int nt = 0; nt < NT; ++nt)
        bf[nt] = *(const sh8*)&ldsB[(wn + nt * 16 + fr) * 64 +
                                    ((((ks << 2) + g) ^ (fr & 7)) << 3)];
#pragma unroll
      for (int mt = 0; mt < MT; ++mt)
#pragma unroll
        for (int nt = 0; nt < NT; ++nt)
          acc[mt][nt] = __builtin_amdgcn_mfma_f32_16x16x32_bf16(af[mt], bf[nt], acc[mt][nt], 0, 0, 0);
    }
    __syncthreads();
  }
}

// ---------------- QKV projection + scatter (BM=64, BN=64 -> 3072 blocks) ----------
__global__ __launch_bounds__(256, 8) void k_qkv_gemm(
    const unsigned short* __restrict__ xb, const unsigned short* __restrict__ wq,
    unsigned short* __restrict__ Q, unsigned short* __restrict__ Kc,
    unsigned short* __restrict__ Vt) {
  __shared__ __align__(16) unsigned short ldsA[64 * 64];    // 8KB
  __shared__ __align__(16) unsigned short ldsB[64 * 64];    // 8KB
  f32x4 acc[2][2];
  const f32x4 fz = {0.f, 0.f, 0.f, 0.f};
#pragma unroll
  for (int i = 0; i < 2; ++i)
#pragma unroll
    for (int j = 0; j < 2; ++j) acc[i][j] = fz;

  const int m0 = blockIdx.x * 64, n0 = blockIdx.y * 64;
  gemm_bt_core<2, 2>(xb, wq, 1024, m0, n0, ldsA, ldsB, acc);

  const int tid = threadIdx.x, wv = tid >> 6, lane = tid & 63;
  const int wm = (wv >> 1) << 5, wn = (wv & 1) << 5;
  const int r4 = (lane >> 4) << 2, fr = lane & 15;
#pragma unroll
  for (int mt = 0; mt < 2; ++mt)
#pragma unroll
    for (int nt = 0; nt < 2; ++nt) {
      const int row0 = m0 + wm + mt * 16 + r4;   // 4-row group, never straddles b
      const int col  = n0 + wn + nt * 16 + fr;   // n in [0,3072)
      const int b = row0 >> 11;
      const int which = col >> 10, rem = col & 1023;
      const int h = rem >> 6, hd = rem & 63;
      const size_t bh = (size_t)(b * 16 + h);
      if (which == 2) {
        const size_t vb = (bh * 64 + hd) * 2048 + (row0 & 2047);
        *(unsigned int*)&Vt[vb]     = pack2(acc[mt][nt][0], acc[mt][nt][1]);
        *(unsigned int*)&Vt[vb + 2] = pack2(acc[mt][nt][2], acc[mt][nt][3]);
      } else {
#pragma unroll
        for (int i = 0; i < 4; ++i) {
          const int lq = (row0 + i) & 2047;
          float v = acc[mt][nt][i];
          if (which == 0) Q [(bh * 2048 + lq) * 64 + hd] = f2b(v * 0.125f);
          else            Kc[(bh * 2048 + lq) * 64 + hd] = f2b(v);
        }
      }
    }
}

// ---------------- causal flash attention (KVBLK=64, LDS-shared K/V) ----------------
// == UNCHANGED from round-20/22 PASSING kernel ==
__global__ __launch_bounds__(256, 4) void k_attn(
    const unsigned short* __restrict__ Q, const unsigned short* __restrict__ Kc,
    const unsigned short* __restrict__ Vt, unsigned short* __restrict__ attn) {
  __shared__ __align__(16) unsigned short kbuf[2][64 * 64];   // 8KB per buf
  __shared__ __align__(16) unsigned short vbuf[2][64 * 64];   // 8KB per buf

  const int bh  = blockIdx.x & 31;
  const int grp = 31 - (blockIdx.x >> 5);      // 0..31, longest first
  const int wv = threadIdx.x >> 6, lane = threadIdx.x & 63;
  const int tid = threadIdx.x;
  const int strip = (grp << 2) + wv;           // 0..127
  const int qw = strip << 4;
  const int b = bh >> 4, h = bh & 15;
  const unsigned short* Qb = Q  + (size_t)bh * 2048 * 64;
  const unsigned short* Kb = Kc + (size_t)bh * 2048 * 64;
  const unsigned short* Vb = Vt + (size_t)bh * 64 * 2048;
  const int fr = lane & 15, g = lane >> 4;
  const int fk = g << 3, r4 = g << 2;
  const f32x4 fz = {0.f, 0.f, 0.f, 0.f};

  // staging map: 512 granules per buffer, 2 per thread
  const int sgr0 = tid >> 3,         sgc0 = tid & 7;         // granule (row, col)
  const int sgr1 = (tid + 256) >> 3, sgc1 = tid & 7;         // second granule

  sh8 qf[2];
#pragma unroll
  for (int ks = 0; ks < 2; ++ks)
    qf[ks] = *(const sh8*)&Qb[(size_t)(qw + fr) * 64 + ks * 32 + fk];

  f32x4 o[4];
#pragma unroll
  for (int i = 0; i < 4; ++i) o[i] = fz;
  float m_i = -1e30f, lp = 0.f;

  const int njm = grp + 1;                     // uniform tile count (incl. diagonal)

  // stage tile 0 into buf 0
  gload_lds16(&Kb[(size_t)sgr0 * 64 + ((sgc0 ^ (sgr0 & 7)) << 3)], &kbuf[0][tid * 8]);
  gload_lds16(&Kb[(size_t)sgr1 * 64 + ((sgc1 ^ (sgr1 & 7)) << 3)], &kbuf[0][(tid + 256) * 8]);
  gload_lds16(&Vb[(size_t)sgr0 * 2048 + ((sgc0 ^ (sgr0 & 7)) << 3)], &vbuf[0][tid * 8]);
  gload_lds16(&Vb[(size_t)sgr1 * 2048 + ((sgc1 ^ (sgr1 & 7)) << 3)], &vbuf[0][(tid + 256) * 8]);

  for (int j = 0; j < njm; ++j) {
    __syncthreads();   // stage(j) complete (vmcnt drain); compute(j-1) done
    if (j + 1 < njm) {
      const int kvn = (j + 1) << 6;
      const int nb = (j + 1) & 1;
      gload_lds16(&Kb[(size_t)(kvn + sgr0) * 64 + ((sgc0 ^ (sgr0 & 7)) << 3)], &kbuf[nb][tid * 8]);
      gload_lds16(&Kb[(size_t)(kvn + sgr1) * 64 + ((sgc1 ^ (sgr1 & 7)) << 3)], &kbuf[nb][(tid + 256) * 8]);
      gload_lds16(&Vb[(size_t)sgr0 * 2048 + kvn + ((sgc0 ^ (sgr0 & 7)) << 3)], &vbuf[nb][tid * 8]);
      gload_lds16(&Vb[(size_t)sgr1 * 2048 + kvn + ((sgc1 ^ (sgr1 & 7)) << 3)], &vbuf[nb][(tid + 256) * 8]);
    }
    const int kvb = j << 6;
    const unsigned short* kb = kbuf[j & 1];
    const unsigned short* vb = vbuf[j & 1];
    // QK^T swapped, 4 independent sub-tiles: s[t] rows kv = kvb+16t+4g+i, col q = fr
    f32x4 s[4];
#pragma unroll
    for (int t = 0; t < 4; ++t) s[t] = fz;
#pragma unroll
    for (int ks = 0; ks < 2; ++ks)
#pragma unroll
      for (int t = 0; t < 4; ++t) {
        sh8 kf = *(const sh8*)&kb[(t * 16 + fr) * 64 + ((((ks << 2) + g) ^ (fr & 7)) << 3)];
        s[t] = __builtin_amdgcn_mfma_f32_16x16x32_bf16(kf, qf[ks], s[t], 0, 0, 0);
      }

    if (j == njm - 1) {  // diagonal tile: causal mask (kv > q)
#pragma unroll
      for (int t = 0; t < 4; ++t)
#pragma unroll
        for (int i = 0; i < 4; ++i)
          if (kvb + t * 16 + r4 + i > qw + fr) s[t][i] = -1e30f;
    }
    // defer-max (T13): common path has NO cross-lane ops
    float pm = s[0][0];
#pragma unroll
    for (int t = 0; t < 4; ++t)
#pragma unroll
      for (int i = 0; i < 4; ++i) pm = fmaxf(pm, s[t][i]);
    if (!__all(pm - m_i <= 8.0f)) {   // rare: full row-max reduce + rescale
      float rm = fmaxf(pm, __shfl_xor(pm, 16, 64));
      rm = fmaxf(rm, __shfl_xor(rm, 32, 64));
      const float mn = fmaxf(m_i, rm);
      const float sc = __expf(m_i - mn);
      m_i = mn;
      lp *= sc;
#pragma unroll
      for (int hb = 0; hb < 4; ++hb)
#pragma unroll
        for (int i = 0; i < 4; ++i) o[hb][i] *= sc;
    }
    // exp in place; lp per-lane partial
#pragma unroll
    for (int t = 0; t < 4; ++t) {
#pragma unroll
      for (int i = 0; i < 4; ++i) s[t][i] = __expf(s[t][i] - m_i);
      lp += (s[t][0] + s[t][1]) + (s[t][2] + s[t][3]);
    }
    // PV per sub-tile: P already in x16 B-frag layout (col q=fr, k=4g+j)
#pragma unroll
    for (int t = 0; t < 4; ++t) {
      union { unsigned int w[2]; sh4 v; } pb;
      pb.w[0] = pack2(s[t][0], s[t][1]);
      pb.w[1] = pack2(s[t][2], s[t][3]);
#pragma unroll
      for (int hb = 0; hb < 4; ++hb) {
        sh4 vf = *(const sh4*)&vb[(hb * 16 + fr) * 64 +
                                  ((((t << 1) + (g >> 1)) ^ (fr & 7)) << 3) + ((g & 1) << 2)];
        o[hb] = mfma16x16x16(vf, pb.v, o[hb]);
      }
    }
  }

  // epilogue: reduce per-lane lp across the 4 g-groups once (r7/r17-validated)
  float l = lp;
  l += __shfl_xor(l, 16, 64);
  l += __shfl_xor(l, 32, 64);
  const float inv = 1.0f / l;
  const size_t base = ((size_t)(b * 2048 + qw + fr)) * 1024 + h * 64;
#pragma unroll
  for (int hb = 0; hb < 4; ++hb)
#pragma unroll
    for (int i2 = 0; i2 < 2; ++i2) {
      unsigned int pw = pack2(o[hb][2 * i2] * inv, o[hb][2 * i2 + 1] * inv);
      *(unsigned int*)&attn[base + hb * 16 + r4 + 2 * i2] = pw;
    }
}

// ---------------- output projection + bias (BM=64, BN=64 -> 1024 blocks) ----------
__global__ __launch_bounds__(256, 5) void k_out_gemm(
    const unsigned short* __restrict__ attn, const unsigned short* __restrict__ wo,
    const float* __restrict__ bias, float* __restrict__ out) {
  __shared__ __align__(16) unsigned short ldsA[64 * 64];    // 8KB
  __shared__ __align__(16) unsigned short ldsB[64 * 64];    // 8KB
  f32x4 acc[2][2];
  const f32x4 fz = {0.f, 0.f, 0.f, 0.f};
#pragma unroll
  for (int i = 0; i < 2; ++i)
#pragma unroll
    for (int j = 0; j < 2; ++j) acc[i][j] = fz;

  const int m0 = blockIdx.x * 64, n0 = blockIdx.y * 64;
  gemm_bt_core<2, 2>(attn, wo, 1024, m0, n0, ldsA, ldsB, acc);

  const int tid = threadIdx.x, wv = tid >> 6, lane = tid & 63;
  const int wm = (wv >> 1) << 5, wn = (wv & 1) << 5;
  const int r4 = (lane >> 4) << 2, fr = lane & 15;
#pragma unroll
  for (int mt = 0; mt < 2; ++mt)
#pragma unroll
    for (int nt = 0; nt < 2; ++nt)
#pragma unroll
      for (int i = 0; i < 4; ++i) {
        int row = m0 + wm + mt * 16 + r4 + i;
        int col = n0 + wn + nt * 16 + fr;
        out[(size_t)row * 1024 + col] = acc[mt][nt][i] + bias[col];
      }
}

// ---------------- launch ----------------
extern "C" void kernel_launch(void* const* d_in, const int* in_sizes, int n_in,
                              void* d_out, int out_size, void* d_ws, size_t ws_size,
                              hipStream_t stream) {
  const float* x     = (const float*)d_in[0];
  const float* qkv_w = (const float*)d_in[1];
  const float* out_w = (const float*)d_in[2];
  const float* out_b = (const float*)d_in[3];
  float* out = (float*)d_out;

  unsigned short* ws   = (unsigned short*)d_ws;
  unsigned short* xb   = ws;                        // 4096*1024
  unsigned short* wq   = xb  + 4096 * 1024;         // 3072*1024
  unsigned short* wo   = wq  + 3072 * 1024;         // 1024*1024
  unsigned short* Qs   = wo  + 1024 * 1024;         // 32*2048*64
  unsigned short* Ks   = Qs  + 32 * 2048 * 64;      // 32*2048*64
  unsigned short* Vts  = Ks  + 32 * 2048 * 64;      // 32*64*2048
  unsigned short* attn = Vts + 32 * 64 * 2048;      // 4096*1024

  k_cvt<<<4096, 256, 0, stream>>>(x,     xb, 4096 * 1024);
  k_cvt<<<3072, 256, 0, stream>>>(qkv_w, wq, 3072 * 1024);
  k_cvt<<<1024, 256, 0, stream>>>(out_w, wo, 1024 * 1024);
  k_qkv_gemm<<<dim3(64, 48), 256, 0, stream>>>(xb, wq, Qs, Ks, Vts);
  k_attn<<<1024, 256, 0, stream>>>(Qs, Ks, Vts, attn);
  k_out_gemm<<<dim3(64, 16), 256, 0, stream>>>(attn, wo, out_b, out);
}

// Round 26
// 106.461 us; speedup vs baseline: 1.0957x; 1.0084x over previous
//
#include <hip/hip_runtime.h>
#include <hip/hip_bf16.h>
#include <cstdint>

// Toy MultiHeadAttention: B=2, L=2048, D=1024, H=16, HD=64, causal, eval (no dropout)
// Pipeline: fused fp32->bf16 convert (one kernel); QKV GEMM (bf16 MFMA, T2-swizzled
// LDS, 64x64 tile) with Q/K/Vt scatter epilogue; causal flash attention (KVBLK=64
// LDS-shared K/V, defer-max, zero-shuffle x16 PV, BALANCED gIdx->grp permutation so
// each CU's 4 resident blocks sum to the mean work); out GEMM (64x64) + bias.

typedef __attribute__((ext_vector_type(8))) short sh8;    // 8 bf16 (4 VGPRs) for 16x16x32
typedef __attribute__((ext_vector_type(4))) short sh4;    // 4 bf16 (2 VGPRs) for 16x16x16
typedef __attribute__((ext_vector_type(4))) float f32x4;  // MFMA C/D frag

__device__ __forceinline__ unsigned short f2b(float f) {  // fp32 -> bf16 RNE
  unsigned int u = __float_as_uint(f);
  u += 0x7FFFu + ((u >> 16) & 1u);
  return (unsigned short)(u >> 16);
}

__device__ __forceinline__ unsigned int pack2(float lo, float hi) {  // 2xbf16 in u32
  return (unsigned int)f2b(lo) | ((unsigned int)f2b(hi) << 16);
}

__device__ __forceinline__ f32x4 mfma16x16x16(sh4 a, sh4 b, f32x4 c) {
#if __has_builtin(__builtin_amdgcn_mfma_f32_16x16x16bf16_1k)
  return __builtin_amdgcn_mfma_f32_16x16x16bf16_1k(a, b, c, 0, 0, 0);
#else
  asm volatile("v_mfma_f32_16x16x16_bf16 %0, %1, %2, %0" : "+v"(c) : "v"(a), "v"(b));
  return c;
#endif
}

__device__ __forceinline__ void gload_lds16(const void* g, void* l) {
  __builtin_amdgcn_global_load_lds((__attribute__((address_space(1))) void*)g,
                                   (__attribute__((address_space(3))) void*)l,
                                   16, 0, 0);
}

// ---------------- fused fp32 -> bf16 convert (x, qkv_w, out_w in one launch) -------
// sizes are exact multiples of 1024 elems/block: x=4096 blocks, qkv_w=3072, out_w=1024.
__global__ __launch_bounds__(256) void k_cvt3(
    const float* __restrict__ x, const float* __restrict__ w1,
    const float* __restrict__ w2, unsigned short* __restrict__ ox,
    unsigned short* __restrict__ o1, unsigned short* __restrict__ o2) {
  const int bid = blockIdx.x;
  const float* in;
  unsigned short* out;
  int base;
  if (bid < 4096)      { in = x;  out = ox; base = bid; }
  else if (bid < 7168) { in = w1; out = o1; base = bid - 4096; }
  else                 { in = w2; out = o2; base = bid - 7168; }
  const int idx = (base * 256 + threadIdx.x) * 4;
  float4 v = *(const float4*)&in[idx];
  union { unsigned short u[4]; uint2 w; } r;
  r.u[0] = f2b(v.x); r.u[1] = f2b(v.y); r.u[2] = f2b(v.z); r.u[3] = f2b(v.w);
  *(uint2*)&out[idx] = r.w;
}

// ---------------- templated GEMM core: C[BM x BN] = A[M,K] * B[N,K]^T ----------------
// BM = MT*32, BN = NT*32; 256 thr = 4 waves in 2x2; wave owns (MT*16)x(NT*16).
// T2 XOR-swizzled LDS (r16/r18/r19/r20-validated), single-buffer staging.
template<int MT, int NT>
__device__ __forceinline__ void gemm_bt_core(
    const unsigned short* __restrict__ A,   // [M][K] bf16 row-major
    const unsigned short* __restrict__ B,   // [N][K] bf16 row-major
    int K, int m0, int n0,
    unsigned short* ldsA, unsigned short* ldsB,
    f32x4 acc[MT][NT]) {
  constexpr int TA = MT;          // A granule-loads per thread (MT*32 rows * 8 / 256)
  constexpr int TB = NT;
  const int tid  = threadIdx.x;
  const int wv   = tid >> 6;
  const int lane = tid & 63;
  const int wm = (wv >> 1) * (MT * 16);
  const int wn = (wv & 1) * (NT * 16);
  const int fr = lane & 15;
  const int g  = lane >> 4;

  for (int k0 = 0; k0 < K; k0 += 64) {
#pragma unroll
    for (int t = 0; t < TA; ++t) {
      int gi = t * 256 + tid;               // granule index (wave-contiguous dest)
      int r = gi >> 3, c = gi & 7;
      gload_lds16(&A[(size_t)(m0 + r) * K + k0 + ((c ^ (r & 7)) << 3)], &ldsA[gi * 8]);
    }
#pragma unroll
    for (int t = 0; t < TB; ++t) {
      int gi = t * 256 + tid;
      int r = gi >> 3, c = gi & 7;
      gload_lds16(&B[(size_t)(n0 + r) * K + k0 + ((c ^ (r & 7)) << 3)], &ldsB[gi * 8]);
    }
    __syncthreads();
#pragma unroll
    for (int ks = 0; ks < 2; ++ks) {
      sh8 af[MT], bf[NT];
#pragma unroll
      for (int mt = 0; mt < MT; ++mt)
        af[mt] = *(const sh8*)&ldsA[(wm + mt * 16 + fr) * 64 +
                                    ((((ks << 2) + g) ^ (fr & 7)) << 3)];
#pragma unroll
      for (int nt = 0; nt < NT; ++nt)
        bf[nt] = *(const sh8*)&ldsB[(wn + nt * 16 + fr) * 64 +
                                    ((((ks << 2) + g) ^ (fr & 7)) << 3)];
#pragma unroll
      for (int mt = 0; mt < MT; ++mt)
#pragma unroll
        for (int nt = 0; nt < NT; ++nt)
          acc[mt][nt] = __builtin_amdgcn_mfma_f32_16x16x32_bf16(af[mt], bf[nt], acc[mt][nt], 0, 0, 0);
    }
    __syncthreads();
  }
}

// ---------------- QKV projection + scatter (BM=64, BN=64 -> 3072 blocks) ----------
__global__ __launch_bounds__(256, 8) void k_qkv_gemm(
    const unsigned short* __restrict__ xb, const unsigned short* __restrict__ wq,
    unsigned short* __restrict__ Q, unsigned short* __restrict__ Kc,
    unsigned short* __restrict__ Vt) {
  __shared__ __align__(16) unsigned short ldsA[64 * 64];    // 8KB
  __shared__ __align__(16) unsigned short ldsB[64 * 64];    // 8KB
  f32x4 acc[2][2];
  const f32x4 fz = {0.f, 0.f, 0.f, 0.f};
#pragma unroll
  for (int i = 0; i < 2; ++i)
#pragma unroll
    for (int j = 0; j < 2; ++j) acc[i][j] = fz;

  const int m0 = blockIdx.x * 64, n0 = blockIdx.y * 64;
  gemm_bt_core<2, 2>(xb, wq, 1024, m0, n0, ldsA, ldsB, acc);

  const int tid = threadIdx.x, wv = tid >> 6, lane = tid & 63;
  const int wm = (wv >> 1) << 5, wn = (wv & 1) << 5;
  const int r4 = (lane >> 4) << 2, fr = lane & 15;
#pragma unroll
  for (int mt = 0; mt < 2; ++mt)
#pragma unroll
    for (int nt = 0; nt < 2; ++nt) {
      const int row0 = m0 + wm + mt * 16 + r4;   // 4-row group, never straddles b
      const int col  = n0 + wn + nt * 16 + fr;   // n in [0,3072)
      const int b = row0 >> 11;
      const int which = col >> 10, rem = col & 1023;
      const int h = rem >> 6, hd = rem & 63;
      const size_t bh = (size_t)(b * 16 + h);
      if (which == 2) {
        const size_t vb = (bh * 64 + hd) * 2048 + (row0 & 2047);
        *(unsigned int*)&Vt[vb]     = pack2(acc[mt][nt][0], acc[mt][nt][1]);
        *(unsigned int*)&Vt[vb + 2] = pack2(acc[mt][nt][2], acc[mt][nt][3]);
      } else {
#pragma unroll
        for (int i = 0; i < 4; ++i) {
          const int lq = (row0 + i) & 2047;
          float v = acc[mt][nt][i];
          if (which == 0) Q [(bh * 2048 + lq) * 64 + hd] = f2b(v * 0.125f);
          else            Kc[(bh * 2048 + lq) * 64 + hd] = f2b(v);
        }
      }
    }
}

// ---------------- causal flash attention (KVBLK=64, balanced CU assignment) --------
// grid: 1024 blocks x 256 thr; blockIdx = gIdx*32 + bh (bh fastest). grp is a
// BALANCED bijective permutation of gIdx: every {k,k+8,k+16,k+24} quadruple (the 4
// blocks co-resident on one CU under round-robin dispatch, 4 blocks/CU exactly,
// no backfill) sums to 62 tile-units -> uniform per-CU wall. Longest still first.
// Per-block body == r20/r22/r25 PASSING kernel, byte-identical.
__global__ __launch_bounds__(256, 4) void k_attn(
    const unsigned short* __restrict__ Q, const unsigned short* __restrict__ Kc,
    const unsigned short* __restrict__ Vt, unsigned short* __restrict__ attn) {
  __shared__ __align__(16) unsigned short kbuf[2][64 * 64];   // 8KB per buf
  __shared__ __align__(16) unsigned short vbuf[2][64 * 64];   // 8KB per buf

  const int bh  = blockIdx.x & 31;
  const int q   = blockIdx.x >> 5;             // 0..31
  const int kq  = q & 7, rowq = q >> 3;
  // balanced permutation: row0 -> 31-k, row1 -> 16+k, row2 -> 15-k, row3 -> k
  const int grp = (rowq == 0) ? (31 - kq) : (rowq == 1) ? (16 + kq)
                : (rowq == 2) ? (15 - kq) : kq;
  const int wv = threadIdx.x >> 6, lane = threadIdx.x & 63;
  const int tid = threadIdx.x;
  const int strip = (grp << 2) + wv;           // 0..127
  const int qw = strip << 4;
  const int b = bh >> 4, h = bh & 15;
  const unsigned short* Qb = Q  + (size_t)bh * 2048 * 64;
  const unsigned short* Kb = Kc + (size_t)bh * 2048 * 64;
  const unsigned short* Vb = Vt + (size_t)bh * 64 * 2048;
  const int fr = lane & 15, g = lane >> 4;
  const int fk = g << 3, r4 = g << 2;
  const f32x4 fz = {0.f, 0.f, 0.f, 0.f};

  // staging map: 512 granules per buffer, 2 per thread
  const int sgr0 = tid >> 3,         sgc0 = tid & 7;         // granule (row, col)
  const int sgr1 = (tid + 256) >> 3, sgc1 = tid & 7;         // second granule

  sh8 qf[2];
#pragma unroll
  for (int ks = 0; ks < 2; ++ks)
    qf[ks] = *(const sh8*)&Qb[(size_t)(qw + fr) * 64 + ks * 32 + fk];

  f32x4 o[4];
#pragma unroll
  for (int i = 0; i < 4; ++i) o[i] = fz;
  float m_i = -1e30f, lp = 0.f;

  const int njm = grp + 1;                     // uniform tile count (incl. diagonal)

  // stage tile 0 into buf 0
  gload_lds16(&Kb[(size_t)sgr0 * 64 + ((sgc0 ^ (sgr0 & 7)) << 3)], &kbuf[0][tid * 8]);
  gload_lds16(&Kb[(size_t)sgr1 * 64 + ((sgc1 ^ (sgr1 & 7)) << 3)], &kbuf[0][(tid + 256) * 8]);
  gload_lds16(&Vb[(size_t)sgr0 * 2048 + ((sgc0 ^ (sgr0 & 7)) << 3)], &vbuf[0][tid * 8]);
  gload_lds16(&Vb[(size_t)sgr1 * 2048 + ((sgc1 ^ (sgr1 & 7)) << 3)], &vbuf[0][(tid + 256) * 8]);

  for (int j = 0; j < njm; ++j) {
    __syncthreads();   // stage(j) complete (vmcnt drain); compute(j-1) done
    if (j + 1 < njm) {
      const int kvn = (j + 1) << 6;
      const int nb = (j + 1) & 1;
      gload_lds16(&Kb[(size_t)(kvn + sgr0) * 64 + ((sgc0 ^ (sgr0 & 7)) << 3)], &kbuf[nb][tid * 8]);
      gload_lds16(&Kb[(size_t)(kvn + sgr1) * 64 + ((sgc1 ^ (sgr1 & 7)) << 3)], &kbuf[nb][(tid + 256) * 8]);
      gload_lds16(&Vb[(size_t)sgr0 * 2048 + kvn + ((sgc0 ^ (sgr0 & 7)) << 3)], &vbuf[nb][tid * 8]);
      gload_lds16(&Vb[(size_t)sgr1 * 2048 + kvn + ((sgc1 ^ (sgr1 & 7)) << 3)], &vbuf[nb][(tid + 256) * 8]);
    }
    const int kvb = j << 6;
    const unsigned short* kb = kbuf[j & 1];
    const unsigned short* vb = vbuf[j & 1];
    // QK^T swapped, 4 independent sub-tiles: s[t] rows kv = kvb+16t+4g+i, col q = fr
    f32x4 s[4];
#pragma unroll
    for (int t = 0; t < 4; ++t) s[t] = fz;
#pragma unroll
    for (int ks = 0; ks < 2; ++ks)
#pragma unroll
      for (int t = 0; t < 4; ++t) {
        sh8 kf = *(const sh8*)&kb[(t * 16 + fr) * 64 + ((((ks << 2) + g) ^ (fr & 7)) << 3)];
        s[t] = __builtin_amdgcn_mfma_f32_16x16x32_bf16(kf, qf[ks], s[t], 0, 0, 0);
      }

    if (j == njm - 1) {  // diagonal tile: causal mask (kv > q)
#pragma unroll
      for (int t = 0; t < 4; ++t)
#pragma unroll
        for (int i = 0; i < 4; ++i)
          if (kvb + t * 16 + r4 + i > qw + fr) s[t][i] = -1e30f;
    }
    // defer-max (T13): common path has NO cross-lane ops
    float pm = s[0][0];
#pragma unroll
    for (int t = 0; t < 4; ++t)
#pragma unroll
      for (int i = 0; i < 4; ++i) pm = fmaxf(pm, s[t][i]);
    if (!__all(pm - m_i <= 8.0f)) {   // rare: full row-max reduce + rescale
      float rm = fmaxf(pm, __shfl_xor(pm, 16, 64));
      rm = fmaxf(rm, __shfl_xor(rm, 32, 64));
      const float mn = fmaxf(m_i, rm);
      const float sc = __expf(m_i - mn);
      m_i = mn;
      lp *= sc;
#pragma unroll
      for (int hb = 0; hb < 4; ++hb)
#pragma unroll
        for (int i = 0; i < 4; ++i) o[hb][i] *= sc;
    }
    // exp in place; lp per-lane partial
#pragma unroll
    for (int t = 0; t < 4; ++t) {
#pragma unroll
      for (int i = 0; i < 4; ++i) s[t][i] = __expf(s[t][i] - m_i);
      lp += (s[t][0] + s[t][1]) + (s[t][2] + s[t][3]);
    }
    // PV per sub-tile: P already in x16 B-frag layout (col q=fr, k=4g+j)
#pragma unroll
    for (int t = 0; t < 4; ++t) {
      union { unsigned int w[2]; sh4 v; } pb;
      pb.w[0] = pack2(s[t][0], s[t][1]);
      pb.w[1] = pack2(s[t][2], s[t][3]);
#pragma unroll
      for (int hb = 0; hb < 4; ++hb) {
        sh4 vf = *(const sh4*)&vb[(hb * 16 + fr) * 64 +
                                  ((((t << 1) + (g >> 1)) ^ (fr & 7)) << 3) + ((g & 1) << 2)];
        o[hb] = mfma16x16x16(vf, pb.v, o[hb]);
      }
    }
  }

  // epilogue: reduce per-lane lp across the 4 g-groups once (r7/r17-validated)
  float l = lp;
  l += __shfl_xor(l, 16, 64);
  l += __shfl_xor(l, 32, 64);
  const float inv = 1.0f / l;
  const size_t base = ((size_t)(b * 2048 + qw + fr)) * 1024 + h * 64;
#pragma unroll
  for (int hb = 0; hb < 4; ++hb)
#pragma unroll
    for (int i2 = 0; i2 < 2; ++i2) {
      unsigned int pw = pack2(o[hb][2 * i2] * inv, o[hb][2 * i2 + 1] * inv);
      *(unsigned int*)&attn[base + hb * 16 + r4 + 2 * i2] = pw;
    }
}

// ---------------- output projection + bias (BM=64, BN=64 -> 1024 blocks) ----------
__global__ __launch_bounds__(256, 5) void k_out_gemm(
    const unsigned short* __restrict__ attn, const unsigned short* __restrict__ wo,
    const float* __restrict__ bias, float* __restrict__ out) {
  __shared__ __align__(16) unsigned short ldsA[64 * 64];    // 8KB
  __shared__ __align__(16) unsigned short ldsB[64 * 64];    // 8KB
  f32x4 acc[2][2];
  const f32x4 fz = {0.f, 0.f, 0.f, 0.f};
#pragma unroll
  for (int i = 0; i < 2; ++i)
#pragma unroll
    for (int j = 0; j < 2; ++j) acc[i][j] = fz;

  const int m0 = blockIdx.x * 64, n0 = blockIdx.y * 64;
  gemm_bt_core<2, 2>(attn, wo, 1024, m0, n0, ldsA, ldsB, acc);

  const int tid = threadIdx.x, wv = tid >> 6, lane = tid & 63;
  const int wm = (wv >> 1) << 5, wn = (wv & 1) << 5;
  const int r4 = (lane >> 4) << 2, fr = lane & 15;
#pragma unroll
  for (int mt = 0; mt < 2; ++mt)
#pragma unroll
    for (int nt = 0; nt < 2; ++nt)
#pragma unroll
      for (int i = 0; i < 4; ++i) {
        int row = m0 + wm + mt * 16 + r4 + i;
        int col = n0 + wn + nt * 16 + fr;
        out[(size_t)row * 1024 + col] = acc[mt][nt][i] + bias[col];
      }
}

// ---------------- launch ----------------
extern "C" void kernel_launch(void* const* d_in, const int* in_sizes, int n_in,
                              void* d_out, int out_size, void* d_ws, size_t ws_size,
                              hipStream_t stream) {
  const float* x     = (const float*)d_in[0];
  const float* qkv_w = (const float*)d_in[1];
  const float* out_w = (const float*)d_in[2];
  const float* out_b = (const float*)d_in[3];
  float* out = (float*)d_out;

  unsigned short* ws   = (unsigned short*)d_ws;
  unsigned short* xb   = ws;                        // 4096*1024
  unsigned short* wq   = xb  + 4096 * 1024;         // 3072*1024
  unsigned short* wo   = wq  + 3072 * 1024;         // 1024*1024
  unsigned short* Qs   = wo  + 1024 * 1024;         // 32*2048*64
  unsigned short* Ks   = Qs  + 32 * 2048 * 64;      // 32*2048*64
  unsigned short* Vts  = Ks  + 32 * 2048 * 64;      // 32*64*2048
  unsigned short* attn = Vts + 32 * 64 * 2048;      // 4096*1024

  k_cvt3<<<8192, 256, 0, stream>>>(x, qkv_w, out_w, xb, wq, wo);
  k_qkv_gemm<<<dim3(64, 48), 256, 0, stream>>>(xb, wq, Qs, Ks, Vts);
  k_attn<<<1024, 256, 0, stream>>>(Qs, Ks, Vts, attn);
  k_out_gemm<<<dim3(64, 16), 256, 0, stream>>>(attn, wo, out_b, out);
}